// Round 20
// baseline (71.020 us; speedup 1.0000x reference)
//
#include <hip/hip_runtime.h>
#include <math.h>

#define T_TOK 8192
#define HDIM 4096
#define NSLOT 128
#define KRET 4
#define TOPK 2048
#define ALPHA 0.1f
#define MAXC 2048

typedef unsigned char uchar;

// ---------- custom 8-bit code (e4m3-style, bias 7, flush < ~2^-7) ----------
// Branchless integer-domain encode (~10 VALU ops) / decode (~8 ops).
// code = clamp((RNE(a) >> 20) - 960, 0, 126); decode = ((code+960)<<20)|sign.
__device__ __forceinline__ unsigned enc1(float f) {
    unsigned u = __float_as_uint(f);
    unsigned a = u & 0x7FFFFFFFu;
    unsigned r = a + 0x7FFFFu + ((a >> 20) & 1u);   // RNE at bit 20
    int code = (int)(r >> 20) - 960;                // ((e-120)<<3)|m3
    code = code < 0 ? 0 : (code > 126 ? 126 : code);
    return ((u >> 24) & 0x80u) | (unsigned)code;
}

__device__ __forceinline__ unsigned enc4(float4 x) {
    return enc1(x.x) | (enc1(x.y) << 8) | (enc1(x.z) << 16) | (enc1(x.w) << 24);
}

__device__ __forceinline__ void dec4(unsigned w, float* o) {
    #pragma unroll
    for (int k = 0; k < 4; k++) {
        unsigned b = (w >> (8 * k)) & 0xFFu;
        unsigned c = b & 0x7Fu;
        unsigned bits = ((b & 0x80u) << 24) | ((c + 960u) << 20);
        o[k] = (c == 0u) ? 0.f : __uint_as_float(bits);
    }
}

// ---------------- Kernel 1: importance + 8-bit copy of h (+ zero rank) -------
__global__ __launch_bounds__(256) void importance_kernel(
    const float* __restrict__ h, const float* __restrict__ attn,
    const float* __restrict__ W, const float* __restrict__ b,
    float* __restrict__ imp, int* __restrict__ rank,
    unsigned* __restrict__ h8)   // [8192][1024] u32 words (4x fp8)
{
    const int wid  = threadIdx.x >> 6;
    const int lane = threadIdx.x & 63;
    const int t = blockIdx.x * 4 + wid;
    const float4* hv = reinterpret_cast<const float4*>(h + (size_t)t * HDIM);
    const float4* Wv = reinterpret_cast<const float4*>(W);
    unsigned* h8row = h8 + (size_t)t * (HDIM / 4);
    float sumsq = 0.f, dot = 0.f;
    #pragma unroll 4
    for (int i = 0; i < 16; i++) {
        float4 x = hv[lane + i * 64];
        float4 w = Wv[lane + i * 64];
        sumsq += x.x * x.x + x.y * x.y + x.z * x.z + x.w * x.w;
        dot   += x.x * w.x + x.y * w.y + x.z * w.z + x.w * w.w;
        h8row[lane + i * 64] = enc4(x);
    }
    #pragma unroll
    for (int off = 32; off > 0; off >>= 1) {
        sumsq += __shfl_down(sumsq, off);
        dot   += __shfl_down(dot, off);
    }
    if (lane == 0) {
        float mag = sqrtf(sumsq);
        float ent = 0.f;
        #pragma unroll
        for (int k = 0; k < KRET; k++) {
            float a = attn[t * KRET + k];
            ent -= a * logf(a + 1e-8f);
        }
        float surprise = ent / logf(4.0f);
        float score = dot + b[0];
        float sig = 1.0f / (1.0f + expf(-score));
        imp[t] = mag * (1.0f + surprise) + sig;
        rank[t] = 0;  // zero for rank_kernel (stream-ordered, replay-safe)
    }
}

// ---------------- Kernel 2: partial rank count, 2-D grid (R4, proven) --------
__global__ __launch_bounds__(256) void rank_kernel(
    const float* __restrict__ imp, int* __restrict__ rank)
{
    const int cb = blockIdx.x & 31;   // candidate block
    const int sl = blockIdx.x >> 5;   // compare slice
    __shared__ float tile[256];
    const int base = sl * 256;
    tile[threadIdx.x] = imp[base + threadIdx.x];
    __syncthreads();
    const int t = cb * 256 + threadIdx.x;
    const float mine = imp[t];
    int r = 0;
    #pragma unroll 8
    for (int i = 0; i < 256; i++) {
        float v = tile[i];
        int s = base + i;
        // jax.lax.top_k tie-break: higher value first, then lower index
        r += (v > mine) || (v == mine && s < t);
    }
    if (r) atomicAdd(&rank[t], r);
}

// ---------------- Kernel 3: per-slot CSR list (R4, proven) -------------------
__global__ __launch_bounds__(256) void slotlist_kernel(
    const int* __restrict__ rank, const int* __restrict__ si,
    int* __restrict__ lists, int* __restrict__ counts)
{
    const int slot = blockIdx.x;
    const int tid = threadIdx.x;
    __shared__ int part[256];
    const int base = tid * 32;
    unsigned mask = 0;
    int local = 0;
    const int4* si4 = reinterpret_cast<const int4*>(si);
    #pragma unroll 8
    for (int j = 0; j < 32; j++) {
        const int t = base + j;
        int4 s = si4[t];
        bool sel = rank[t] < TOPK;
        bool mem = (s.x == slot) | (s.y == slot) | (s.z == slot) | (s.w == slot);
        if (sel && mem) { mask |= (1u << j); local++; }
    }
    part[tid] = local;
    __syncthreads();
    for (int off = 1; off < 256; off <<= 1) {
        int v = part[tid];
        int add = (tid >= off) ? part[tid - off] : 0;
        __syncthreads();
        part[tid] = v + add;
        __syncthreads();
    }
    int pos = part[tid] - local;  // exclusive prefix
    int* mylist = lists + (size_t)slot * MAXC;
    for (int j = 0; j < 32; j++) {
        if (mask & (1u << j)) mylist[pos++] = base + j;
    }
    if (tid == 255) counts[slot] = part[255];
}

// ---------------- Kernel 4: CSR gather over 8-bit rows + EMA -----------------
// R4's proven structure; only the gathered dtype changes (u32 of 4x fp8).
// Logical gather traffic: 32.5 MB vs 130 MB f32.
__global__ __launch_bounds__(256) void update_kernel(
    const unsigned* __restrict__ h8, const float* __restrict__ mem,
    const int* __restrict__ lists, const int* __restrict__ counts,
    float* __restrict__ out)
{
    const int slot = blockIdx.x >> 2;   // 128 slots
    const int chunk = blockIdx.x & 3;   // 4 chunks of 256 u32 words
    const int cnt = counts[slot];
    __shared__ int s_list[MAXC];
    for (int i = threadIdx.x; i < cnt; i += 256)
        s_list[i] = lists[(size_t)slot * MAXC + i];
    __syncthreads();

    const int dword = chunk * 256 + threadIdx.x;  // word index in 1024-word row
    float4 acc = make_float4(0.f, 0.f, 0.f, 0.f);
    float v[4];
    int i = 0;
    for (; i + 4 <= cnt; i += 4) {
        unsigned q0 = h8[(size_t)s_list[i]     * (HDIM / 4) + dword];
        unsigned q1 = h8[(size_t)s_list[i + 1] * (HDIM / 4) + dword];
        unsigned q2 = h8[(size_t)s_list[i + 2] * (HDIM / 4) + dword];
        unsigned q3 = h8[(size_t)s_list[i + 3] * (HDIM / 4) + dword];
        dec4(q0, v); acc.x += v[0]; acc.y += v[1]; acc.z += v[2]; acc.w += v[3];
        dec4(q1, v); acc.x += v[0]; acc.y += v[1]; acc.z += v[2]; acc.w += v[3];
        dec4(q2, v); acc.x += v[0]; acc.y += v[1]; acc.z += v[2]; acc.w += v[3];
        dec4(q3, v); acc.x += v[0]; acc.y += v[1]; acc.z += v[2]; acc.w += v[3];
    }
    for (; i < cnt; i++) {
        unsigned q0 = h8[(size_t)s_list[i] * (HDIM / 4) + dword];
        dec4(q0, v); acc.x += v[0]; acc.y += v[1]; acc.z += v[2]; acc.w += v[3];
    }

    const size_t o = (size_t)slot * HDIM + (size_t)dword * 4;
    float4 cur = *reinterpret_cast<const float4*>(mem + o);
    float4 r;
    if (cnt > 0) {
        float inv = 1.0f / (float)cnt;
        r.x = ALPHA * (acc.x * inv) + (1.f - ALPHA) * cur.x;
        r.y = ALPHA * (acc.y * inv) + (1.f - ALPHA) * cur.y;
        r.z = ALPHA * (acc.z * inv) + (1.f - ALPHA) * cur.z;
        r.w = ALPHA * (acc.w * inv) + (1.f - ALPHA) * cur.w;
    } else {
        r = cur;
    }
    *reinterpret_cast<float4*>(out + o) = r;
}

extern "C" void kernel_launch(void* const* d_in, const int* in_sizes, int n_in,
                              void* d_out, int out_size, void* d_ws, size_t ws_size,
                              hipStream_t stream) {
    const float* h    = (const float*)d_in[0];  // [8192, 4096]
    const float* attn = (const float*)d_in[1];  // [8192, 4]
    const int*   si   = (const int*)d_in[2];    // [8192, 4]
    const float* mem  = (const float*)d_in[3];  // [1, 128, 4096]
    const float* W    = (const float*)d_in[4];  // [1, 4096]
    const float* b    = (const float*)d_in[5];  // [1]
    float* out = (float*)d_out;                 // [1, 128, 4096]

    char* ws = (char*)d_ws;
    float*    imp    = (float*)(ws);             // 8192 f32
    int*      rank   = (int*)(ws + 32768);       // 8192 i32
    int*      counts = (int*)(ws + 65536);       // 128 i32
    int*      lists  = (int*)(ws + 131072);      // 128 x 2048 i32 (1 MB)
    unsigned* h8     = (unsigned*)(ws + 2097152);// 8192 x 1024 u32 (32 MB)

    importance_kernel<<<T_TOK / 4, 256, 0, stream>>>(h, attn, W, b, imp, rank, h8);
    rank_kernel<<<1024, 256, 0, stream>>>(imp, rank);
    slotlist_kernel<<<NSLOT, 256, 0, stream>>>(rank, si, lists, counts);
    update_kernel<<<NSLOT * 4, 256, 0, stream>>>(h8, mem, lists, counts, out);
}

// Round 21
// 59.865 us; speedup vs baseline: 1.1863x; 1.1863x over previous
//
#include <hip/hip_runtime.h>
#include <math.h>

#define T_TOK 8192
#define HDIM 4096
#define NSLOT 128
#define KRET 4
#define TOPK 2048
#define ALPHA 0.1f
#define MAXC 2048   // hard bound: a slot appears at most once per selected token

// ---------------- Kernel 1: per-token importance (+ zero rank) ----------------
// At HBM roofline: streams all 128 MB of hidden_states at >=85% peak.
__global__ __launch_bounds__(256) void importance_kernel(
    const float* __restrict__ h, const float* __restrict__ attn,
    const float* __restrict__ W, const float* __restrict__ b,
    float* __restrict__ imp, int* __restrict__ rank)
{
    const int wid  = threadIdx.x >> 6;
    const int lane = threadIdx.x & 63;
    const int t = blockIdx.x * 4 + wid;
    const float4* hv = reinterpret_cast<const float4*>(h + (size_t)t * HDIM);
    const float4* Wv = reinterpret_cast<const float4*>(W);
    float sumsq = 0.f, dot = 0.f;
    #pragma unroll 4
    for (int i = 0; i < 16; i++) {
        float4 x = hv[lane + i * 64];
        float4 w = Wv[lane + i * 64];
        sumsq += x.x * x.x + x.y * x.y + x.z * x.z + x.w * x.w;
        dot   += x.x * w.x + x.y * w.y + x.z * w.z + x.w * w.w;
    }
    #pragma unroll
    for (int off = 32; off > 0; off >>= 1) {
        sumsq += __shfl_down(sumsq, off);
        dot   += __shfl_down(dot, off);
    }
    if (lane == 0) {
        float mag = sqrtf(sumsq);
        float ent = 0.f;
        #pragma unroll
        for (int k = 0; k < KRET; k++) {
            float a = attn[t * KRET + k];
            ent -= a * logf(a + 1e-8f);
        }
        float surprise = ent / logf(4.0f);
        float score = dot + b[0];
        float sig = 1.0f / (1.0f + expf(-score));
        imp[t] = mag * (1.0f + surprise) + sig;
        rank[t] = 0;  // zero for rank_kernel (stream-ordered, replay-safe)
    }
}

// ---------------- Kernel 2: partial rank count, 2-D grid ----------------
__global__ __launch_bounds__(256) void rank_kernel(
    const float* __restrict__ imp, int* __restrict__ rank)
{
    const int cb = blockIdx.x & 31;   // candidate block
    const int sl = blockIdx.x >> 5;   // compare slice
    __shared__ float tile[256];
    const int base = sl * 256;
    tile[threadIdx.x] = imp[base + threadIdx.x];
    __syncthreads();
    const int t = cb * 256 + threadIdx.x;
    const float mine = imp[t];
    int r = 0;
    #pragma unroll 8
    for (int i = 0; i < 256; i++) {
        float v = tile[i];
        int s = base + i;
        // jax.lax.top_k tie-break: higher value first, then lower index
        r += (v > mine) || (v == mine && s < t);
    }
    if (r) atomicAdd(&rank[t], r);
}

// ---------------- Kernel 3: per-slot CSR list, direct from rank+si ----------
// One block per slot; ordered compaction (ascending t) -> deterministic.
__global__ __launch_bounds__(256) void slotlist_kernel(
    const int* __restrict__ rank, const int* __restrict__ si,
    int* __restrict__ lists, int* __restrict__ counts)
{
    const int slot = blockIdx.x;
    const int tid = threadIdx.x;
    __shared__ int part[256];
    const int base = tid * 32;
    unsigned mask = 0;
    int local = 0;
    const int4* si4 = reinterpret_cast<const int4*>(si);
    #pragma unroll 8
    for (int j = 0; j < 32; j++) {
        const int t = base + j;
        int4 s = si4[t];
        bool sel = rank[t] < TOPK;
        bool mem = (s.x == slot) | (s.y == slot) | (s.z == slot) | (s.w == slot);
        if (sel && mem) { mask |= (1u << j); local++; }
    }
    part[tid] = local;
    __syncthreads();
    for (int off = 1; off < 256; off <<= 1) {
        int v = part[tid];
        int add = (tid >= off) ? part[tid - off] : 0;
        __syncthreads();
        part[tid] = v + add;
        __syncthreads();
    }
    int pos = part[tid] - local;  // exclusive prefix
    int* mylist = lists + (size_t)slot * MAXC;
    for (int j = 0; j < 32; j++) {
        if (mask & (1u << j)) mylist[pos++] = base + j;
    }
    if (tid == 255) counts[slot] = part[255];
}

// ---------------- Kernel 4: CSR gather + segment-mean + EMA ----------------
// Empirically at its gather-throughput bound: invariant under 4x parallelism
// (R7), XCD placement (R16), fp8 byte-shrink (R17/R20); LDS-scatter (R13/14)
// and MFMA (R15) forms all regressed. ~63 rows/block through L3 fabric.
__global__ __launch_bounds__(256) void update_kernel(
    const float* __restrict__ h, const float* __restrict__ mem,
    const int* __restrict__ lists, const int* __restrict__ counts,
    float* __restrict__ out)
{
    const int slot = blockIdx.x >> 2;   // 128 slots
    const int chunk = blockIdx.x & 3;   // 4 chunks of 1024 floats
    const int cnt = counts[slot];
    __shared__ int s_list[MAXC];
    for (int i = threadIdx.x; i < cnt; i += 256)
        s_list[i] = lists[(size_t)slot * MAXC + i];
    __syncthreads();

    const int dbase = chunk * 1024 + threadIdx.x * 4;
    float4 acc = make_float4(0.f, 0.f, 0.f, 0.f);
    int i = 0;
    for (; i + 4 <= cnt; i += 4) {
        int t0 = s_list[i], t1 = s_list[i + 1];
        int t2 = s_list[i + 2], t3 = s_list[i + 3];
        float4 x0 = *reinterpret_cast<const float4*>(h + (size_t)t0 * HDIM + dbase);
        float4 x1 = *reinterpret_cast<const float4*>(h + (size_t)t1 * HDIM + dbase);
        float4 x2 = *reinterpret_cast<const float4*>(h + (size_t)t2 * HDIM + dbase);
        float4 x3 = *reinterpret_cast<const float4*>(h + (size_t)t3 * HDIM + dbase);
        acc.x += x0.x + x1.x + x2.x + x3.x;
        acc.y += x0.y + x1.y + x2.y + x3.y;
        acc.z += x0.z + x1.z + x2.z + x3.z;
        acc.w += x0.w + x1.w + x2.w + x3.w;
    }
    for (; i < cnt; i++) {
        int t0 = s_list[i];
        float4 x0 = *reinterpret_cast<const float4*>(h + (size_t)t0 * HDIM + dbase);
        acc.x += x0.x; acc.y += x0.y; acc.z += x0.z; acc.w += x0.w;
    }

    const size_t o = (size_t)slot * HDIM + dbase;
    float4 cur = *reinterpret_cast<const float4*>(mem + o);
    float4 r;
    if (cnt > 0) {
        float inv = 1.0f / (float)cnt;
        r.x = ALPHA * (acc.x * inv) + (1.f - ALPHA) * cur.x;
        r.y = ALPHA * (acc.y * inv) + (1.f - ALPHA) * cur.y;
        r.z = ALPHA * (acc.z * inv) + (1.f - ALPHA) * cur.z;
        r.w = ALPHA * (acc.w * inv) + (1.f - ALPHA) * cur.w;
    } else {
        r = cur;
    }
    *reinterpret_cast<float4*>(out + o) = r;
}

extern "C" void kernel_launch(void* const* d_in, const int* in_sizes, int n_in,
                              void* d_out, int out_size, void* d_ws, size_t ws_size,
                              hipStream_t stream) {
    const float* h    = (const float*)d_in[0];  // [8192, 4096]
    const float* attn = (const float*)d_in[1];  // [8192, 4]
    const int*   si   = (const int*)d_in[2];    // [8192, 4]
    const float* mem  = (const float*)d_in[3];  // [1, 128, 4096]
    const float* W    = (const float*)d_in[4];  // [1, 4096]
    const float* b    = (const float*)d_in[5];  // [1]
    float* out = (float*)d_out;                 // [1, 128, 4096]

    char* ws = (char*)d_ws;
    float* imp    = (float*)(ws);            // 8192 f32
    int*   rank   = (int*)(ws + 32768);      // 8192 i32
    int*   counts = (int*)(ws + 65536);      // 128 i32
    int*   lists  = (int*)(ws + 131072);     // 128 x 2048 i32 (1 MB)

    importance_kernel<<<T_TOK / 4, 256, 0, stream>>>(h, attn, W, b, imp, rank);
    rank_kernel<<<1024, 256, 0, stream>>>(imp, rank);
    slotlist_kernel<<<NSLOT, 256, 0, stream>>>(rank, si, lists, counts);
    update_kernel<<<NSLOT * 4, 256, 0, stream>>>(h, mem, lists, counts, out);
}